// Round 2
// baseline (277.917 us; speedup 1.0000x reference)
//
#include <hip/hip_runtime.h>

// Spline2D fused kernel, v4: one block per image (1024 blocks x 256 threads).
// v3 post-mortem: 16384 tiny blocks (16 KB written each, 4 stores/thread) were
// block-churn-bound at ~2.8 TB/s write BW while fill hits 6.3 TB/s. This version
// gives each wave 64 independent nt float4 stores (full 256-row image per block)
// so the store pipeline stays full and block turnover drops 16x.
//   prologue: rb[r][k] = sum_i wx[i]*coeffs[r+2+i][k+2]  (65x68, 17.7 KB LDS)
//   stream:   64 iters/thread; patch rows blend from rb in regs, rest store 0.

#define CW 72   // coeffs leading dim (64 + 2*4)

typedef float f4 __attribute__((ext_vector_type(4)));

__device__ __forceinline__ void st_nt(float* p, f4 v) {
    __builtin_nontemporal_store(v, reinterpret_cast<f4*>(p));
}

__global__ __launch_bounds__(256) void spline2d_fused4(
    const float* __restrict__ coeffs,
    const float* __restrict__ x,
    const float* __restrict__ y,
    float* __restrict__ out)
{
    __shared__ float rb[65][68];     // row-blended coeffs, 17.7 KB

    const int b = blockIdx.x;        // image index

    const float xv = x[b];           // block-uniform -> scalar loads
    const float yv = y[b];
    const float fx = floorf(xv), fy = floorf(yv);
    const int   R0 = (int)fx + 96;   // patch top row in output
    const int   C0 = (int)fy + 96;   // patch left col in output
    const float sx = xv - fx, sy = yv - fy;

    float wx0, wx1, wx2, wx3, wy0, wy1, wy2, wy3;
    {
        const float p = sx, p2 = p * p, p3 = p2 * p, q = 1.0f - p;
        wx0 = p3 * (1.0f / 6.0f);
        wx1 = -0.5f * p3 + 0.5f * p2 + 0.5f * p + (1.0f / 6.0f);
        wx2 = 0.5f * p3 - p2 + (2.0f / 3.0f);
        wx3 = q * q * q * (1.0f / 6.0f);
    }
    {
        const float p = sy, p2 = p * p, p3 = p2 * p, q = 1.0f - p;
        wy0 = p3 * (1.0f / 6.0f);
        wy1 = -0.5f * p3 + 0.5f * p2 + 0.5f * p + (1.0f / 6.0f);
        wy2 = 0.5f * p3 - p2 + (2.0f / 3.0f);
        wy3 = q * q * q * (1.0f / 6.0f);
    }

    const int t    = threadIdx.x;
    const int w    = t >> 6;         // wave id 0..3
    const int lane = t & 63;

    // ---- prologue: row blend into LDS. 4 rows per pass (one per wave). ----
    // coeffs is 20.7 KB -> L1/L2 resident; loads are independent & pipelined.
#pragma unroll
    for (int pass = 0; pass < 17; ++pass) {
        const int r = (pass << 2) + w;       // 0..67 (wave-uniform)
        if (r <= 64) {
            const float* p0 = coeffs + (r + 2) * CW + 2;
            rb[r][lane] = p0[lane] * wx0 + p0[lane + CW] * wx1 +
                          p0[lane + 2 * CW] * wx2 + p0[lane + 3 * CW] * wx3;
            if (lane < 4) {
                const int k = 64 + lane;
                rb[r][k] = p0[k] * wx0 + p0[k + CW] * wx1 +
                           p0[k + 2 * CW] * wx2 + p0[k + 3 * CW] * wx3;
            }
        }
    }
    __syncthreads();

    // ---- stream phase: 64 rows per wave, 1 nt float4 store per iteration ----
    float* __restrict__ obase = out + ((size_t)b << 16);
    const int  col4 = lane << 2;     // 0,4,...,252
    const int  c0   = col4 - C0;     // patch col of this thread's element 0
    const bool cin  = (c0 >= -3 && c0 <= 64);
    const f4   z4   = {0.f, 0.f, 0.f, 0.f};

#pragma unroll 8
    for (int it = 0; it < 64; ++it) {
        const int row = (it << 2) + w;       // wave-uniform
        const int r   = row - R0;            // patch row index
        f4 v = z4;
        if ((unsigned)r <= 64u && cin) {     // row test wave-uniform
#pragma unroll
            for (int m = 0; m < 4; ++m) {
                const int c = c0 + m;
                if ((unsigned)c <= 64u) {
                    v[m] = rb[r][c] * wy0 + rb[r][c + 1] * wy1 +
                           rb[r][c + 2] * wy2 + rb[r][c + 3] * wy3;
                }
            }
        }
        st_nt(obase + (row << 8) + col4, v);
    }
}

extern "C" void kernel_launch(void* const* d_in, const int* in_sizes, int n_in,
                              void* d_out, int out_size, void* d_ws, size_t ws_size,
                              hipStream_t stream) {
    const float* coeffs = (const float*)d_in[0];  // (72,72)
    const float* x      = (const float*)d_in[1];  // (1024,)
    const float* y      = (const float*)d_in[2];  // (1024,)
    float* out = (float*)d_out;                   // (1024,1,256,256)

    const int batch = in_sizes[1];                // 1024
    spline2d_fused4<<<batch, 256, 0, stream>>>(coeffs, x, y, out);
}

// Round 3
// 268.894 us; speedup vs baseline: 1.0336x; 1.0336x over previous
//
#include <hip/hip_runtime.h>

// Spline2D v5: memset + patch-only kernel.
// v2/v3/v4 post-mortem: all full-output-write variants cap at ~2.6-2.8 TB/s
// write BW regardless of block granularity / store depth / LDS usage, while
// the runtime fillBuffer kernel hits 6.37 TB/s on the same buffer. The output
// is 93.6% zeros, so: zero everything via hipMemsetAsync (runtime fill path,
// ~43 us for 256 MiB), then write ONLY the 65x65 patch per image (~17 MB).
//   patch kernel: 1024 blocks x 256 thr; row-blend into LDS (65x68, 17.7 KB),
//   then 17 row-passes of predicated scalar stores (lane=col, +1 col by lane0).

#define CW 72   // coeffs leading dim (64 + 2*4)

__global__ __launch_bounds__(256) void spline2d_patch(
    const float* __restrict__ coeffs,
    const float* __restrict__ x,
    const float* __restrict__ y,
    float* __restrict__ out)
{
    __shared__ float rb[65][68];     // row-blended coeffs, 17.7 KB

    const int b = blockIdx.x;        // image index

    const float xv = x[b];           // block-uniform -> scalar loads
    const float yv = y[b];
    const float fx = floorf(xv), fy = floorf(yv);
    const int   R0 = (int)fx + 96;   // patch top row in output
    const int   C0 = (int)fy + 96;   // patch left col in output
    const float sx = xv - fx, sy = yv - fy;

    float wx0, wx1, wx2, wx3, wy0, wy1, wy2, wy3;
    {
        const float p = sx, p2 = p * p, p3 = p2 * p, q = 1.0f - p;
        wx0 = p3 * (1.0f / 6.0f);
        wx1 = -0.5f * p3 + 0.5f * p2 + 0.5f * p + (1.0f / 6.0f);
        wx2 = 0.5f * p3 - p2 + (2.0f / 3.0f);
        wx3 = q * q * q * (1.0f / 6.0f);
    }
    {
        const float p = sy, p2 = p * p, p3 = p2 * p, q = 1.0f - p;
        wy0 = p3 * (1.0f / 6.0f);
        wy1 = -0.5f * p3 + 0.5f * p2 + 0.5f * p + (1.0f / 6.0f);
        wy2 = 0.5f * p3 - p2 + (2.0f / 3.0f);
        wy3 = q * q * q * (1.0f / 6.0f);
    }

    const int t    = threadIdx.x;
    const int w    = t >> 6;         // wave id 0..3
    const int lane = t & 63;

    // ---- prologue: row blend into LDS. 4 rows per pass (one per wave). ----
    // coeffs is 20.7 KB -> L1/L2 resident after first touch.
#pragma unroll
    for (int pass = 0; pass < 17; ++pass) {
        const int r = (pass << 2) + w;       // 0..67 (wave-uniform)
        if (r <= 64) {
            const float* p0 = coeffs + (r + 2) * CW + 2;
            rb[r][lane] = p0[lane] * wx0 + p0[lane + CW] * wx1 +
                          p0[lane + 2 * CW] * wx2 + p0[lane + 3 * CW] * wx3;
            if (lane < 4) {
                const int k = 64 + lane;
                rb[r][k] = p0[k] * wx0 + p0[k + CW] * wx1 +
                           p0[k + 2 * CW] * wx2 + p0[k + 3 * CW] * wx3;
            }
        }
    }
    __syncthreads();

    // ---- patch write: 65 rows x 65 cols, predicated against image bounds ----
    float* __restrict__ obase = out + ((size_t)b << 16);
#pragma unroll
    for (int it = 0; it < 17; ++it) {
        const int r = (it << 2) + w;         // patch row 0..64 (wave-uniform)
        if (r > 64) continue;                // only w>0 at it==16
        const int orow = R0 + r;
        if ((unsigned)orow > 255u) continue; // clipped rows -> sliced off
        float* __restrict__ orp = obase + (orow << 8);

        // cols 0..63 (one per lane)
        {
            const int c  = lane;
            const int oc = C0 + c;
            const float v = rb[r][c] * wy0 + rb[r][c + 1] * wy1 +
                            rb[r][c + 2] * wy2 + rb[r][c + 3] * wy3;
            if ((unsigned)oc <= 255u) orp[oc] = v;
        }
        // col 64 (lane 0)
        if (lane == 0) {
            const int oc = C0 + 64;
            const float v = rb[r][64] * wy0 + rb[r][65] * wy1 +
                            rb[r][66] * wy2 + rb[r][67] * wy3;
            if ((unsigned)oc <= 255u) orp[oc] = v;
        }
    }
}

extern "C" void kernel_launch(void* const* d_in, const int* in_sizes, int n_in,
                              void* d_out, int out_size, void* d_ws, size_t ws_size,
                              hipStream_t stream) {
    const float* coeffs = (const float*)d_in[0];  // (72,72)
    const float* x      = (const float*)d_in[1];  // (1024,)
    const float* y      = (const float*)d_in[2];  // (1024,)
    float* out = (float*)d_out;                   // (1024,1,256,256)

    const int batch = in_sizes[1];                // 1024
    const size_t out_bytes = (size_t)batch * 256 * 256 * sizeof(float);

    // Zero the whole output via the runtime fill path (~6.4 TB/s), then
    // overwrite only the nonzero 65x65 patch per image.
    hipMemsetAsync(d_out, 0, out_bytes, stream);
    spline2d_patch<<<batch, 256, 0, stream>>>(coeffs, x, y, out);
}

// Round 4
// 258.644 us; speedup vs baseline: 1.0745x; 1.0396x over previous
//
#include <hip/hip_runtime.h>

// Spline2D fused single-pass kernel, v6 == v2 (revert to empirical best).
// Session post-mortem (v3: no-LDS-staging, v4: fat grid-stride blocks,
// v5: memset+patch-only): all four structurally different variants land in a
// 260-278us band uncorrelated with estimated GPU work; our kernel never
// appears in the rocprof top-5 (every top dispatch is the harness's 1 GiB
// re-poison fill at ~161us). Conclusion: dur_us = fixed re-poison fill
// + our work + fixed overhead; v2 writes the minimum byte count (every
// output byte exactly once, plain coalesced float4 stores) and is the
// twice-measured best (259.0 / 260.2 us). Keep it.
//
// Block = 256 threads covers 16 rows (4096 floats) of one image.
// Fast path (block-uniform test, ~65% of blocks): pure 4x float4 zero stores.
// Slow path: separable spline blend staged in LDS --
//   step1: rb[slot][k]  = sum_i wx[i]*coeffs[r+2+i][k+2]   (1088 elems)
//   step2: tmpl[slot][col] = sum_j wy[j]*rb[slot][c+j] or 0 (branch-free rows)
//   store: 4x aligned float4 LDS reads + 4x float4 global stores.

#define CW 72   // coeffs leading dim (64 + 2*4)

__global__ __launch_bounds__(256) void spline2d_fused2(
    const float* __restrict__ coeffs,
    const float* __restrict__ x,
    const float* __restrict__ y,
    float* __restrict__ out)
{
    __shared__ float rb[16][68];     // row-blended coeffs (4.25 KB)
    __shared__ float tmpl[16][256];  // full output rows for this segment (16 KB)

    const int blk    = blockIdx.x;
    const int b      = blk >> 4;     // image index (block-uniform)
    const int seg    = blk & 15;     // 16-row segment within image
    const int Rstart = seg << 4;

    const float xv = x[b];           // block-uniform -> scalar
    const float yv = y[b];
    const float fx = floorf(xv), fy = floorf(yv);
    const int   R0 = (int)fx + 96;   // patch top row in output
    const int   C0 = (int)fy + 96;   // patch left col in output

    const int t         = threadIdx.x;
    const int rowInPass = t >> 6;        // 0..3 (wave-uniform)
    const int col4      = (t & 63) << 2; // 0,4,...,252

    float* __restrict__ obase =
        out + ((size_t)b << 16) + ((size_t)Rstart << 8);
    const float4 z4 = make_float4(0.f, 0.f, 0.f, 0.f);

    // Block-uniform: does this 16-row segment intersect patch rows [R0, R0+64]?
    if (R0 > Rstart + 15 || R0 + 64 < Rstart) {
#pragma unroll
        for (int u = 0; u < 4; ++u) {
            *reinterpret_cast<float4*>(obase + (u << 10) + (rowInPass << 8) + col4) = z4;
        }
        return;
    }

    // ---- slow path: build the 16 output rows in LDS, then stream them out ----
    const float sx = xv - fx, sy = yv - fy;
    float wx[4], wy[4];
    {
        const float p = sx, p2 = p * p, p3 = p2 * p, q = 1.0f - p;
        wx[0] = p3 * (1.0f / 6.0f);
        wx[1] = -0.5f * p3 + 0.5f * p2 + 0.5f * p + (1.0f / 6.0f);
        wx[2] = 0.5f * p3 - p2 + (2.0f / 3.0f);
        wx[3] = q * q * q * (1.0f / 6.0f);
    }
    {
        const float p = sy, p2 = p * p, p3 = p2 * p, q = 1.0f - p;
        wy[0] = p3 * (1.0f / 6.0f);
        wy[1] = -0.5f * p3 + 0.5f * p2 + 0.5f * p + (1.0f / 6.0f);
        wy[2] = 0.5f * p3 - p2 + (2.0f / 3.0f);
        wy[3] = q * q * q * (1.0f / 6.0f);
    }

    // step1: row blend. slot = row within segment; r = patch row index.
    for (int idx = t; idx < 16 * 68; idx += 256) {
        const int slot = idx / 68;
        const int k    = idx - slot * 68;        // 0..67
        const int r    = Rstart + slot - R0;
        float v = 0.0f;
        if ((unsigned)r <= 64u) {
            const float* p0 = coeffs + (r + 2) * CW + (k + 2);
            v = p0[0] * wx[0] + p0[CW] * wx[1] + p0[2 * CW] * wx[2] + p0[3 * CW] * wx[3];
        }
        rb[slot][k] = v;
    }
    __syncthreads();

    // step2: col blend into full 256-wide rows (zeros outside patch cols).
    for (int k2 = t; k2 < 16 * 256; k2 += 256) {
        const int slot = k2 >> 8;
        const int col  = k2 & 255;
        const int r    = Rstart + slot - R0;
        const int c    = col - C0;               // patch col
        float v = 0.0f;
        if ((unsigned)r <= 64u && (unsigned)c <= 64u) {
            v = rb[slot][c] * wy[0] + rb[slot][c + 1] * wy[1] +
                rb[slot][c + 2] * wy[2] + rb[slot][c + 3] * wy[3];
        }
        tmpl[slot][col] = v;
    }
    __syncthreads();

    // store phase: identical shape to the fast path, values from LDS.
#pragma unroll
    for (int u = 0; u < 4; ++u) {
        const int slot = (u << 2) + rowInPass;
        const float4 v = *reinterpret_cast<const float4*>(&tmpl[slot][col4]);
        *reinterpret_cast<float4*>(obase + (u << 10) + (rowInPass << 8) + col4) = v;
    }
}

extern "C" void kernel_launch(void* const* d_in, const int* in_sizes, int n_in,
                              void* d_out, int out_size, void* d_ws, size_t ws_size,
                              hipStream_t stream) {
    const float* coeffs = (const float*)d_in[0];  // (72,72)
    const float* x      = (const float*)d_in[1];  // (1024,)
    const float* y      = (const float*)d_in[2];  // (1024,)
    float* out = (float*)d_out;                   // (1024,1,256,256)

    const int batch = in_sizes[1];                // 1024
    spline2d_fused2<<<batch * 16, 256, 0, stream>>>(coeffs, x, y, out);
}